// Round 4
// baseline (50274.731 us; speedup 1.0000x reference)
//
#include <hip/hip_runtime.h>
#include <math.h>

static constexpr int Bsz = 64;
static constexpr int Tt  = 512;
static constexpr int INF = 256;
static constexpr int Hf  = 512;
static constexpr int OUTF = 10;
static constexpr int NBLK = 256;   // 128 col-groups x 2 batch-halves
static constexpr int NTHR = 1024;  // 16 waves

__device__ __forceinline__ float sigmoidf_(float x) {
    return 1.0f / (1.0f + __expf(-x));
}
__device__ __forceinline__ float tanhf_(float x) {
    float ax = fabsf(x);
    float e = __expf(-2.0f * ax);
    float r = (1.0f - e) / (1.0f + e);
    return copysignf(r, x);
}

// Agent-scope (LLC-coherent) accesses; no fences, no L2 writeback/invalidate.
__device__ __forceinline__ float ldc(const float* p) {
    return __hip_atomic_load(const_cast<float*>(p), __ATOMIC_RELAXED, __HIP_MEMORY_SCOPE_AGENT);
}
__device__ __forceinline__ void stc(float* p, float v) {
    __hip_atomic_store(p, v, __ATOMIC_RELAXED, __HIP_MEMORY_SCOPE_AGENT);
}
__device__ __forceinline__ unsigned long long ldcu64(const float* p) {
    return __hip_atomic_load((unsigned long long*)p, __ATOMIC_RELAXED, __HIP_MEMORY_SCOPE_AGENT);
}

// LDS-visibility barrier WITHOUT draining vmcnt (keeps global loads in flight).
__device__ __forceinline__ void block_sync_lds() {
    asm volatile("s_waitcnt lgkmcnt(0)" ::: "memory");
    __builtin_amdgcn_sched_barrier(0);
    __builtin_amdgcn_s_barrier();
}
// Producer side of grid barrier: drain my stores, block-barrier, set flag.
__device__ __forceinline__ void arrive(unsigned* flags, int myflag, unsigned gen) {
    asm volatile("s_waitcnt vmcnt(0) lgkmcnt(0)" ::: "memory");
    __builtin_amdgcn_sched_barrier(0);
    __builtin_amdgcn_s_barrier();
    if (threadIdx.x == 0)
        __hip_atomic_store(&flags[myflag], gen, __ATOMIC_RELAXED, __HIP_MEMORY_SCOPE_AGENT);
}
// Consumer side: poll 128 flags of my batch-half, then block-barrier.
__device__ __forceinline__ void waitbar(unsigned* flags, int pollbase, unsigned gen) {
    if (threadIdx.x < 128) {
        unsigned* f = &flags[pollbase + threadIdx.x];
        while (__hip_atomic_load(f, __ATOMIC_RELAXED, __HIP_MEMORY_SCOPE_AGENT) < gen)
            __builtin_amdgcn_s_sleep(1);
    }
    __builtin_amdgcn_s_barrier();
}

// x (B,T,IN) -> xT (T,IN,B)
__global__ __launch_bounds__(256) void transpose_x_k(const float* __restrict__ x,
                                                     float* __restrict__ xT) {
    __shared__ float tile[64][65];
    int t  = blockIdx.x;
    int k0 = blockIdx.y * 64;
    int tid = threadIdx.x;
#pragma unroll
    for (int i = 0; i < 16; ++i) {
        int idx = i * 256 + tid;
        int bb = idx >> 6, kk = idx & 63;
        tile[bb][kk] = x[(size_t)bb * Tt * INF + (size_t)t * INF + k0 + kk];
    }
    __syncthreads();
#pragma unroll
    for (int i = 0; i < 16; ++i) {
        int idx = i * 256 + tid;
        int kk = idx >> 6, bb = idx & 63;
        xT[(size_t)t * INF * 64 + (size_t)(k0 + kk) * 64 + bb] = tile[bb][kk];
    }
}

#define FMA2(a, w, v) { (a).x = fmaf((w).x, (v), (a).x); (a).y = fmaf((w).y, (v), (a).y); }
#define W2(base, idx) (((const float2*)(base))[(size_t)(idx) * 2 + cs])

// x-part GEMV over rows [wv*LIN/16, +LIN/16) for two matrices sharing x loads.
template<int LIN>
__device__ __forceinline__ void xpair(const float* __restrict__ xt, int bidx, int wv, int cs,
                                      const float4* mA, const float4* mB,
                                      float2& aA, float2& aB) {
    const float* xb = xt + bidx;
    const int k0 = wv * (LIN / 16);
#pragma unroll 8
    for (int k = k0; k < k0 + LIN / 16; ++k) {
        float xv = xb[k * 64];
        float2 w = W2(mA, k); FMA2(aA, w, xv);
        w = W2(mB, k);        FMA2(aB, w, xv);
    }
}
template<int LIN>
__device__ __forceinline__ void xone(const float* __restrict__ xt, int bidx, int wv, int cs,
                                     const float4* mA, float2& aA) {
    const float* xb = xt + bidx;
    const int k0 = wv * (LIN / 16);
#pragma unroll 8
    for (int k = k0; k < k0 + LIN / 16; ++k) {
        float xv = xb[k * 64];
        float2 w = W2(mA, k); FMA2(aA, w, xv);
    }
}

// Persistent layer kernel. Block (cg,bh): cols [cg*4,+4), batches [bh*32,+32).
// 3 grid-sync phases per step; remote state staged into LDS in 16KB chunks.
template<int LIN, bool WRITE_Y>
__global__ __launch_bounds__(NTHR) void esn_persist_k(
    const float* __restrict__ xT, float* __restrict__ y,
    float* rA, float* rB, float* hA, float* hB,
    float* rhB, float* hgB,
    const float* __restrict__ Win, const float* __restrict__ Wres,
    const float* __restrict__ Wz, const float* __restrict__ bz,
    const float* __restrict__ Wr, const float* __restrict__ br,
    const float* __restrict__ Wc, const float* __restrict__ bc,
    const float* __restrict__ Wg, const float* __restrict__ bg,
    const float* __restrict__ Wp, const float* __restrict__ bp,
    unsigned* flags)
{
    constexpr int R4 = LIN + 512;
    constexpr int ROWS = 4 * R4 + LIN + 3 * 512;   // 5*LIN + 3584

    extern __shared__ char smem[];
    float4* wRES = (float4*)smem;
    float4* wZ   = wRES + R4;
    float4* wR   = wZ + R4;
    float4* wC   = wR + R4;
    float4* wGx  = wC + R4;
    float4* wGh  = wGx + LIN;
    float4* wGr  = wGh + 512;
    float4* wP   = wGr + 512;
    float*  stg  = (float*)smem + (size_t)ROWS * 4;  // 8192 floats: 2 bufs x 4096
    float*  pb   = stg;                              // reduction partials alias staging
    float*  lz   = stg + 8192;                       // [4][32] locals
    float*  lgx  = lz + 128;
    float*  lp   = lgx + 128;
    float*  lgg  = lp + 128;
    float*  lhg  = lgg + 128;

    const int tid  = threadIdx.x;
    const int lane = tid & 63;
    const int wv   = tid >> 6;
    const int b    = lane & 31;
    const int cs   = lane >> 5;
    const int cg   = blockIdx.x & 127;
    const int bh   = blockIdx.x >> 7;
    const int c0   = cg * 4;
    const int boff = bh * 32;
    const int bidx = boff + b;
    const int myflag = bh * 128 + cg;
    const int pollbase = bh * 128;

    // staging slot identity
    const int srow = (tid >> 4) & 63;
    const int sbp  = tid & 15;
    const int srC0 = tid >> 4;

    // reduce-thread identity
    const int rm   = tid >> 7;
    const int rrem = tid & 127;
    const int rc_  = rrem >> 5;
    const int rb   = rrem & 31;
    const int pl   = (rb + 32 * (rc_ >> 1)) * 2 + (rc_ & 1);
    const int cab  = c0 + rc_;
    const int gi   = cab * 64 + boff + rb;

    // ---- stage this block's 4 columns of every matrix into LDS
    for (int k = tid; k < LIN; k += NTHR) {
        wRES[k] = *(const float4*)&Win[(size_t)k * 512 + c0];
        wGx[k]  = *(const float4*)&Wg[(size_t)k * 512 + c0];
    }
    for (int k = tid; k < R4; k += NTHR) {
        wZ[k] = *(const float4*)&Wz[(size_t)k * 512 + c0];
        wR[k] = *(const float4*)&Wr[(size_t)k * 512 + c0];
        wC[k] = *(const float4*)&Wc[(size_t)k * 512 + c0];
    }
    for (int k = tid; k < 512; k += NTHR) {
        wRES[LIN + k] = *(const float4*)&Wres[(size_t)k * 512 + c0];
        wGh[k] = *(const float4*)&Wg[(size_t)(LIN + k) * 512 + c0];
        wGr[k] = *(const float4*)&Wg[(size_t)(LIN + 512 + k) * 512 + c0];
        wP[k]  = *(const float4*)&Wp[(size_t)k * 512 + c0];
    }
    __syncthreads();

    float* rc = rA; float* rn = rB; float* hc = hA; float* hn = hB;
    unsigned gen = 0;

    // prologue: x-parts for t=0
    float2 zx = {0,0}, rsx = {0,0}, resx = {0,0}, gxx = {0,0}, cxx = {0,0};
    xpair<LIN>(xT, bidx, wv, cs, wZ, wR, zx, rsx);
    xpair<LIN>(xT, bidx, wv, cs, wRES, wGx, resx, gxx);

    for (int t = 0; t < Tt; ++t) {
        const float* xt = xT + (size_t)t * LIN * 64;

        // ================= phase A: r_new, z, rh, gx =================
        waitbar(flags, pollbase, gen);     // gen==3t; trivially passes at t=0
        float rcown = 0.f, hown = 0.f;
        if (tid < 512) {
            if (rm == 0) rcown = ldc(rc + gi);
            else if (rm == 2) hown = ldc(hc + gi);
        }
        {
            unsigned long long v0, v1, n0 = 0, n1 = 0;
            {
                size_t o0 = (size_t)srow * 64 + boff + sbp * 2;
                v0 = ldcu64(hc + o0); v1 = ldcu64(rc + o0);
            }
            for (int c = 0; c < 8; ++c) {
                if (c < 7) {
                    size_t on = (size_t)((c + 1) * 64 + srow) * 64 + boff + sbp * 2;
                    n0 = ldcu64(hc + on); n1 = ldcu64(rc + on);
                }
                float* sbuf = stg + (c & 1) * 4096;
                *(unsigned long long*)&sbuf[(size_t)srow * 32 + sbp * 2] = v0;
                *(unsigned long long*)&sbuf[(size_t)(64 + srow) * 32 + sbp * 2] = v1;
                block_sync_lds();
                const float* sb = stg + (c & 1) * 4096;
#pragma unroll
                for (int rr = 0; rr < 4; ++rr) {
                    int row = wv * 4 + rr;
                    float hv = sb[row * 32 + b];
                    float rv = sb[(64 + row) * 32 + b];
                    int k = LIN + c * 64 + row;
                    float2 w;
                    w = W2(wZ, k);   FMA2(zx, w, hv);
                    w = W2(wR, k);   FMA2(rsx, w, hv);
                    w = W2(wRES, k); FMA2(resx, w, rv);
                }
                v0 = n0; v1 = n1;
            }
        }
        __builtin_amdgcn_s_barrier();      // staging reads done before pb clobber
        {
            float2* pb2 = (float2*)pb;
            pb2[(0 * 16 + wv) * 64 + lane] = resx;
            pb2[(1 * 16 + wv) * 64 + lane] = zx;
            pb2[(2 * 16 + wv) * 64 + lane] = rsx;
            pb2[(3 * 16 + wv) * 64 + lane] = gxx;
        }
        block_sync_lds();
        if (tid < 512) {
            float s = 0.f;
#pragma unroll
            for (int w = 0; w < 16; ++w) s += pb[(rm * 16 + w) * 128 + pl];
            if (rm == 0)      stc(rn + gi, 0.7f * rcown + 0.3f * tanhf_(s));
            else if (rm == 1) lz[rrem] = sigmoidf_(s + bz[cab]);
            else if (rm == 2) stc(rhB + gi, sigmoidf_(s + br[cab]) * hown);
            else              lgx[rrem] = s;
        }
        arrive(flags, myflag, ++gen);
        // hide flag latency: cand x-part for this step
        cxx.x = 0.f; cxx.y = 0.f;
        xone<LIN>(xt, bidx, wv, cs, wC, cxx);
        waitbar(flags, pollbase, gen);

        // ================= phase B: h_gru, p, gg =================
        float hownB = 0.f;
        if (tid < 128) hownB = ldc(hc + gi);
        float2 pacc = {0,0}, gracc = {0,0};
        {
            unsigned long long v0, v1, n0 = 0, n1 = 0;
            {
                size_t o0 = (size_t)srow * 64 + boff + sbp * 2;
                v0 = ldcu64(rn + o0); v1 = ldcu64(rhB + o0);
            }
            for (int c = 0; c < 8; ++c) {
                if (c < 7) {
                    size_t on = (size_t)((c + 1) * 64 + srow) * 64 + boff + sbp * 2;
                    n0 = ldcu64(rn + on); n1 = ldcu64(rhB + on);
                }
                float* sbuf = stg + (c & 1) * 4096;
                *(unsigned long long*)&sbuf[(size_t)srow * 32 + sbp * 2] = v0;
                *(unsigned long long*)&sbuf[(size_t)(64 + srow) * 32 + sbp * 2] = v1;
                block_sync_lds();
                const float* sb = stg + (c & 1) * 4096;
#pragma unroll
                for (int rr = 0; rr < 4; ++rr) {
                    int row = wv * 4 + rr;
                    float rnv = sb[row * 32 + b];
                    float rhv = sb[(64 + row) * 32 + b];
                    int k = c * 64 + row;
                    float2 w;
                    w = W2(wC, LIN + k); FMA2(cxx, w, rhv);
                    w = W2(wP, k);       FMA2(pacc, w, rnv);
                    w = W2(wGr, k);      FMA2(gracc, w, rnv);
                }
                v0 = n0; v1 = n1;
            }
        }
        __builtin_amdgcn_s_barrier();
        {
            float2* pb2 = (float2*)pb;
            pb2[(0 * 16 + wv) * 64 + lane] = cxx;
            pb2[(1 * 16 + wv) * 64 + lane] = pacc;
            pb2[(2 * 16 + wv) * 64 + lane] = gracc;
        }
        block_sync_lds();
        if (tid < 384) {
            float s = 0.f;
#pragma unroll
            for (int w = 0; w < 16; ++w) s += pb[(rm * 16 + w) * 128 + pl];
            if (rm == 0) {
                float cand = tanhf_(s + bc[cab]);
                float zv = lz[rrem];
                float hg = (1.f - zv) * hownB + zv * cand;
                stc(hgB + gi, hg);
                lhg[rrem] = hg;
            } else if (rm == 1) {
                lp[rrem] = tanhf_(s + bp[cab]);
            } else {
                lgg[rrem] = s + lgx[rrem];
            }
        }
        arrive(flags, myflag, ++gen);
        // hide flag latency: next step's gx and Win-x parts
        gxx.x = 0.f; gxx.y = 0.f; resx.x = 0.f; resx.y = 0.f;
        if (t + 1 < Tt)
            xpair<LIN>(xT + (size_t)(t + 1) * LIN * 64, bidx, wv, cs, wRES, wGx, resx, gxx);
        waitbar(flags, pollbase, gen);

        // ================= phase C: g, h_new =================
        float2 ghacc = {0,0};
        {
            unsigned long long v0, v1, n0 = 0, n1 = 0;
            {
                size_t o0 = (size_t)srC0 * 64 + boff + sbp * 2;
                size_t o1 = (size_t)(64 + srC0) * 64 + boff + sbp * 2;
                v0 = ldcu64(hgB + o0); v1 = ldcu64(hgB + o1);
            }
            for (int c = 0; c < 4; ++c) {
                if (c < 3) {
                    size_t on0 = (size_t)((c + 1) * 128 + srC0) * 64 + boff + sbp * 2;
                    size_t on1 = (size_t)((c + 1) * 128 + 64 + srC0) * 64 + boff + sbp * 2;
                    n0 = ldcu64(hgB + on0); n1 = ldcu64(hgB + on1);
                }
                float* sbuf = stg + (c & 1) * 4096;
                *(unsigned long long*)&sbuf[(size_t)srC0 * 32 + sbp * 2] = v0;
                *(unsigned long long*)&sbuf[(size_t)(64 + srC0) * 32 + sbp * 2] = v1;
                block_sync_lds();
                const float* sb = stg + (c & 1) * 4096;
#pragma unroll
                for (int rr = 0; rr < 8; ++rr) {
                    int row = wv * 8 + rr;
                    float hgv = sb[row * 32 + b];
                    int k = c * 128 + row;
                    float2 w = W2(wGh, k);
                    FMA2(ghacc, w, hgv);
                }
                v0 = n0; v1 = n1;
            }
        }
        __builtin_amdgcn_s_barrier();
        ((float2*)pb)[(0 * 16 + wv) * 64 + lane] = ghacc;
        block_sync_lds();
        if (tid < 128) {
            float s = 0.f;
#pragma unroll
            for (int w = 0; w < 16; ++w) s += pb[w * 128 + pl];
            float g = sigmoidf_(s + lgg[rrem] + bg[cab]);
            float hnv = (1.f - g) * lhg[rrem] + g * lp[rrem];
            stc(hn + gi, hnv);
            if (WRITE_Y) y[(size_t)t * (Hf * 64) + gi] = hnv;
        }
        arrive(flags, myflag, ++gen);
        // hide flag latency: next step's z/reset x-parts
        zx.x = 0.f; zx.y = 0.f; rsx.x = 0.f; rsx.y = 0.f;
        if (t + 1 < Tt)
            xpair<LIN>(xT + (size_t)(t + 1) * LIN * 64, bidx, wv, cs, wZ, wR, zx, rsx);

        float* tp = rc; rc = rn; rn = tp;
        tp = hc; hc = hn; hn = tp;
    }
}

// Head: hid = relu(last@Wo1 + bo1)
__global__ __launch_bounds__(256) void head1_k(const float* __restrict__ hlast,
                                               const float* __restrict__ Wo1,
                                               const float* __restrict__ bo1,
                                               float* __restrict__ hidT) {
    int tid = threadIdx.x;
    int b = tid & 63, jg = tid >> 6;
    int j0 = blockIdx.x * 16 + jg * 4;
    float acc[4] = {0.f, 0.f, 0.f, 0.f};
    const float* ap = hlast + b;
    const float* wp = Wo1 + j0;
#pragma unroll 4
    for (int k = 0; k < Hf; ++k) {
        float xv = ap[k * 64];
        const float4 w = *reinterpret_cast<const float4*>(wp + k * 512);
        acc[0] = fmaf(w.x, xv, acc[0]);
        acc[1] = fmaf(w.y, xv, acc[1]);
        acc[2] = fmaf(w.z, xv, acc[2]);
        acc[3] = fmaf(w.w, xv, acc[3]);
    }
#pragma unroll
    for (int jj = 0; jj < 4; ++jj) {
        int j = j0 + jj;
        hidT[j * 64 + b] = fmaxf(acc[jj] + bo1[j], 0.f);
    }
}

__global__ __launch_bounds__(640) void head2_k(const float* __restrict__ hidT,
                                               const float* __restrict__ Wo2,
                                               const float* __restrict__ bo2,
                                               float* __restrict__ out) {
    int tid = threadIdx.x;
    if (tid >= Bsz * OUTF) return;
    int b = tid / OUTF, o = tid % OUTF;
    float acc = 0.f;
    for (int k = 0; k < Hf; ++k)
        acc = fmaf(hidT[k * 64 + b], Wo2[k * OUTF + o], acc);
    out[tid] = acc + bo2[o];
}

struct LayerW {
    const float *Win, *Wres, *Wz, *bz, *Wr, *br, *Wc, *bc, *Wg, *bg, *Wp, *bp;
};

extern "C" void kernel_launch(void* const* d_in, const int* in_sizes, int n_in,
                              void* d_out, int out_size, void* d_ws, size_t ws_size,
                              hipStream_t stream) {
    const float* x = (const float*)d_in[0];
    LayerW L[2];
    int idx = 1;
    for (int li = 0; li < 2; ++li) {
        L[li].Win  = (const float*)d_in[idx++];
        L[li].Wres = (const float*)d_in[idx++];
        L[li].Wz   = (const float*)d_in[idx++];
        L[li].bz   = (const float*)d_in[idx++];
        L[li].Wr   = (const float*)d_in[idx++];
        L[li].br   = (const float*)d_in[idx++];
        L[li].Wc   = (const float*)d_in[idx++];
        L[li].bc   = (const float*)d_in[idx++];
        L[li].Wg   = (const float*)d_in[idx++];
        L[li].bg   = (const float*)d_in[idx++];
        L[li].Wp   = (const float*)d_in[idx++];
        L[li].bp   = (const float*)d_in[idx++];
    }
    const float* Wo1 = (const float*)d_in[idx++];
    const float* bo1 = (const float*)d_in[idx++];
    const float* Wo2 = (const float*)d_in[idx++];
    const float* bo2 = (const float*)d_in[idx++];

    char* ws = (char*)d_ws;
    size_t off = 0;
    auto walloc = [&](size_t bytes) -> float* {
        float* p = (float*)(ws + off);
        off += (bytes + 255) & ~(size_t)255;
        return p;
    };
    const size_t STATE = (size_t)Hf * 64 * sizeof(float); // 128 KiB
    float* xT0 = walloc((size_t)Tt * INF * 64 * sizeof(float)); // 33.5 MB
    float* y0  = walloc((size_t)Tt * Hf * 64 * sizeof(float));  // 67 MB
    float* rA  = walloc(STATE);
    float* rB  = walloc(STATE);
    float* hA  = walloc(STATE);
    float* hB  = walloc(STATE);
    float* rhB = walloc(STATE);
    float* hgB = walloc(STATE);
    float* hidT = walloc(STATE);
    unsigned* flags = (unsigned*)walloc(NBLK * sizeof(unsigned));
    (void)ws_size;

    // dynamic LDS: ROWS*16 + 32768 (staging/pb) + 2560 (locals)
    constexpr unsigned SMEM0 = (5 * INF + 3584) * 16 + 32768 + 2560; // 113,152
    constexpr unsigned SMEM1 = (5 * Hf  + 3584) * 16 + 32768 + 2560; // 133,632
    hipFuncSetAttribute((const void*)esn_persist_k<INF, true>,
                        hipFuncAttributeMaxDynamicSharedMemorySize, SMEM0);
    hipFuncSetAttribute((const void*)esn_persist_k<Hf, false>,
                        hipFuncAttributeMaxDynamicSharedMemorySize, SMEM1);

    transpose_x_k<<<dim3(Tt, INF / 64), 256, 0, stream>>>(x, xT0);

    // ---- layer 0
    hipMemsetAsync(flags, 0, NBLK * sizeof(unsigned), stream);
    hipMemsetAsync(rA, 0, STATE, stream);
    hipMemsetAsync(hA, 0, STATE, stream);
    esn_persist_k<INF, true><<<NBLK, NTHR, SMEM0, stream>>>(
        xT0, y0, rA, rB, hA, hB, rhB, hgB,
        L[0].Win, L[0].Wres, L[0].Wz, L[0].bz, L[0].Wr, L[0].br,
        L[0].Wc, L[0].bc, L[0].Wg, L[0].bg, L[0].Wp, L[0].bp, flags);

    // ---- layer 1
    hipMemsetAsync(flags, 0, NBLK * sizeof(unsigned), stream);
    hipMemsetAsync(rA, 0, STATE, stream);
    hipMemsetAsync(hA, 0, STATE, stream);
    esn_persist_k<Hf, false><<<NBLK, NTHR, SMEM1, stream>>>(
        y0, nullptr, rA, rB, hA, hB, rhB, hgB,
        L[1].Win, L[1].Wres, L[1].Wz, L[1].bz, L[1].Wr, L[1].br,
        L[1].Wc, L[1].bc, L[1].Wg, L[1].bg, L[1].Wp, L[1].bp, flags);

    // 512 steps (even) -> final h is back in hA.
    head1_k<<<dim3(32, 1), 256, 0, stream>>>(hA, Wo1, bo1, hidT);
    head2_k<<<dim3(1, 1), 640, 0, stream>>>(hidT, Wo2, bo2, (float*)d_out);
}